// Round 4
// baseline (1095.728 us; speedup 1.0000x reference)
//
#include <hip/hip_runtime.h>
#include <hip/hip_cooperative_groups.h>
#include <math.h>

namespace cg = cooperative_groups;

typedef unsigned short u16;
typedef short s8v __attribute__((ext_vector_type(8)));   // 8 bf16 = one MFMA A/B frag
typedef float f4v __attribute__((ext_vector_type(4)));   // MFMA C/D frag

__device__ inline float b2f(u16 u) {
    union { unsigned int i; float f; } v; v.i = ((unsigned int)u) << 16; return v.f;
}
__device__ inline u16 f2b(float f) {  // round-to-nearest-even
    unsigned int x = __float_as_uint(f);
    return (u16)((x + 0x7fffu + ((x >> 16) & 1u)) >> 16);
}
__device__ inline float ldf(const void* p, size_t i, int f32) {
    return f32 ? ((const float*)p)[i] : b2f(((const u16*)p)[i]);
}
__device__ inline s8v load8(const void* p, size_t idx, int f32) {
    if (f32) {
        const float* f = (const float*)p + idx;
        float4 a = *(const float4*)(f);
        float4 b = *(const float4*)(f + 4);
        s8v r;
        r[0] = (short)f2b(a.x); r[1] = (short)f2b(a.y);
        r[2] = (short)f2b(a.z); r[3] = (short)f2b(a.w);
        r[4] = (short)f2b(b.x); r[5] = (short)f2b(b.y);
        r[6] = (short)f2b(b.z); r[7] = (short)f2b(b.w);
        return r;
    }
    return *(const s8v*)((const u16*)p + idx);
}

// ===========================================================================
// MEGA-KERNEL PATH: whole pipeline in one cooperative launch, 256 blocks x 512
// threads (1 block/CU), grid.sync() between stages. Stage bodies = R3 logic.
// ===========================================================================
struct MP {
    const void *x, *G1, *G3; const int *eidx, *perm; const void *lam, *beta;
    const void *W1,*b1,*W2,*b2,*W3,*b3,*W1h,*b1h,*W3h,*b3h,*W2m,*b2m,*W3m,*b3m;
    const void *Wqkv_mix,*bqkv_mix,*Wo_mix,*bo_mix,*Wqkv_fus,*bqkv_fus,*Wo_fus,*bo_fus,*Wc,*bc;
    void* out;
    u16 *G1b,*Zt0,*Zt1,*Zt2,*Zt3,*h1,*h2,*h3c1,*h1mix,*h2mix,*h3c2,*Ph1,*Ph3,*xin,*qkv,*obar,*mir;
    float *part0,*part1,*part2;
};

// Feature GEMM stage: out = A[M,128] @ W + bias over all 256 blocks.
// Row-slices of 16, one 16x16 col-tile per wave, 128-col passes.
__device__ void feat_stage(char* smemc, int bid, int tid, int f32,
                           const void* A, int aF32,
                           const void* W, const void* bias, int wLayout,
                           int M, int Nc, int outMode, void* outp, u16* mir, int outF32) {
    u16* Wt = (u16*)smemc;               // [128][136]
    u16* At = (u16*)(smemc + 34816);     // [16][136]
    const int w = tid >> 6, lane = tid & 63, l15 = lane & 15, quad = lane >> 4;
    const int nSl = M >> 4;
    for (int cb = 0; cb < Nc; cb += 128) {
        __syncthreads();   // prior smem users done
        if (wLayout == 1) {
            for (int c = tid; c < 2048; c += 512) {
                int n = c >> 4, kb = c & 15;
                *(s8v*)(Wt + n * 136 + kb * 8) = load8(W, (size_t)(cb + n) * 128 + kb * 8, f32);
            }
        } else {   // W[128][Nc]
            for (int idx = tid; idx < 16384; idx += 512) {
                int k = idx >> 7, n = idx & 127;
                Wt[n * 136 + k] = f2b(ldf(W, (size_t)k * Nc + cb + n, f32));
            }
        }
        __syncthreads();
        for (int sl = bid; sl < nSl; sl += 256) {
            if (tid < 256) {
                int r = tid >> 4, kb = tid & 15;
                *(s8v*)(At + r * 136 + kb * 8) = load8(A, (size_t)(sl * 16 + r) * 128 + kb * 8, aF32);
            }
            __syncthreads();
            f4v acc = {};
#pragma unroll
            for (int ks = 0; ks < 4; ++ks) {
                s8v a = *(const s8v*)(At + l15 * 136 + ks * 32 + quad * 8);
                s8v b = *(const s8v*)(Wt + (w * 16 + l15) * 136 + ks * 32 + quad * 8);
                acc = __builtin_amdgcn_mfma_f32_16x16x32_bf16(a, b, acc, 0, 0, 0);
            }
            int col = cb + w * 16 + l15;
            float bv = ldf(bias, col, f32);
            if (outMode == 1) {          // transposed Zt[col][M]
                ushort4 o4;
                o4.x = f2b(acc[0] + bv); o4.y = f2b(acc[1] + bv);
                o4.z = f2b(acc[2] + bv); o4.w = f2b(acc[3] + bv);
                *(ushort4*)((u16*)outp + (size_t)col * M + sl * 16 + quad * 4) = o4;
            } else if (outMode == 0) {   // [M][Nc] bf16
#pragma unroll
                for (int r = 0; r < 4; ++r) {
                    int row = sl * 16 + quad * 4 + r;
                    ((u16*)outp)[(size_t)row * Nc + col] = f2b(acc[r] + bv);
                }
            } else {                     // outMode 2: final h3 -> d_out + mirror
#pragma unroll
                for (int r = 0; r < 4; ++r) {
                    int row = sl * 16 + quad * 4 + r;
                    float v = acc[r] + bv;
                    u16 vb = f2b(v);
                    mir[(size_t)row * 128 + col] = vb;
                    if (outF32) ((float*)outp)[262144 + (size_t)row * 128 + col] = v;
                    else        ((u16*)outp)[262144 + (size_t)row * 128 + col] = vb;
                }
            }
            __syncthreads();
        }
    }
}

// Big propagation GEMM stage: one 128-row x 512-k tile per block (id in [0,256)).
__device__ void big_stage(char* smemc, int tid, int id, const void* G, int gF32,
                          const u16* Zt, float* part) {
    u16* At = (u16*)smemc;                // [128][72]
    u16* Bt = (u16*)(smemc + 18432);      // [128][72]
    const int rowBase = (id & 31) * 128;
    const int kChunk = (id >> 5) * 512;
    const int w = tid >> 6, lane = tid & 63;
    const int wm = w & 1, wn = w >> 1;
    const int l15 = lane & 15, quad = lane >> 4;
    const int r0 = tid >> 3, kb = tid & 7, r1 = 64 + (tid >> 3);
    f4v acc[4][2] = {};
    for (int it = 0; it < 8; ++it) {
        const int kBase = kChunk + it * 64;
        s8v ga0 = load8(G, (size_t)(rowBase + r0) * 4096 + kBase + kb * 8, gF32);
        s8v gb0 = *(const s8v*)(Zt + (size_t)r0 * 4096 + kBase + kb * 8);
        s8v ga1 = load8(G, (size_t)(rowBase + r1) * 4096 + kBase + kb * 8, gF32);
        s8v gb1 = *(const s8v*)(Zt + (size_t)r1 * 4096 + kBase + kb * 8);
        __syncthreads();   // prior ds_reads (or prior stage's smem use) done
        *(s8v*)(At + r0 * 72 + kb * 8) = ga0;
        *(s8v*)(Bt + r0 * 72 + kb * 8) = gb0;
        *(s8v*)(At + r1 * 72 + kb * 8) = ga1;
        *(s8v*)(Bt + r1 * 72 + kb * 8) = gb1;
        __syncthreads();
#pragma unroll
        for (int ks = 0; ks < 2; ++ks) {
            s8v a[4], b[2];
            const int kq = ks * 4 + quad;
#pragma unroll
            for (int mi = 0; mi < 4; ++mi)
                a[mi] = *(const s8v*)(At + (wm * 64 + mi * 16 + l15) * 72 + kq * 8);
#pragma unroll
            for (int ni = 0; ni < 2; ++ni)
                b[ni] = *(const s8v*)(Bt + (wn * 32 + ni * 16 + l15) * 72 + kq * 8);
#pragma unroll
            for (int mi = 0; mi < 4; ++mi)
#pragma unroll
                for (int ni = 0; ni < 2; ++ni)
                    acc[mi][ni] = __builtin_amdgcn_mfma_f32_16x16x32_bf16(
                        a[mi], b[ni], acc[mi][ni], 0, 0, 0);
        }
    }
    float* pbase = part + (size_t)(id >> 5) * 524288;
#pragma unroll
    for (int mi = 0; mi < 4; ++mi)
#pragma unroll
        for (int ni = 0; ni < 2; ++ni) {
            int row = rowBase + wm * 64 + mi * 16 + quad * 4;
            int col = wn * 32 + ni * 16 + l15;
#pragma unroll
            for (int r = 0; r < 4; ++r)
                pbase[(size_t)(row + r) * 128 + col] = acc[mi][ni][r];
        }
}

// Split-K(8) reduce + epilogue; gid in [0,131072) covers vec4 of 524288 elems.
__device__ void epi_one(int gid, const float* part, const u16* res, u16* outb,
                        int mode, float bscale) {
    int i = gid * 4;
    f4v t = {};
#pragma unroll
    for (int s = 0; s < 8; ++s)
        t += *(const f4v*)(part + (size_t)s * 524288 + i);
    u16 o[4];
#pragma unroll
    for (int j = 0; j < 4; ++j) {
        float v = t[j];
        if (mode == 1 || mode == 2) v += b2f(res[i + j]);
        if (mode <= 2) v = fmaxf(v, 0.0f);
        if (mode == 2) v *= bscale;
        o[j] = f2b(v);
    }
    *(ushort4*)(outb + i) = make_ushort4(o[0], o[1], o[2], o[3]);
}

__device__ void mix_stage(int gid, const u16* Ph1, const u16* Ph3,
                          const int* perm, float l, u16* xin) {
    for (int i = gid; i < 524288; i += 131072) {
        int n = i >> 7, h = i & 127;
        int pn = perm[n];
        float a = l * b2f(Ph1[i]) + (1.0f - l) * b2f(Ph1[(size_t)pn * 128 + h]);
        float b = l * b2f(Ph3[i]) + (1.0f - l) * b2f(Ph3[(size_t)pn * 128 + h]);
        xin[i] = f2b(a);
        xin[524288 + i] = f2b(b);
    }
}

__device__ void attn_stage(int bid, int tid, const u16* qkv, u16* obar, int nh) {
    int w = tid >> 6, lane = tid & 63;
    int hd = 128 / nh;
    float scale = 1.0f / sqrtf((float)hd);
    for (int n = bid * 8 + w; n < 4096; n += 2048) {
        const u16* r0 = qkv + (size_t)n * 384;
        const u16* r1 = qkv + (size_t)(4096 + n) * 384;
        float ov[2];
#pragma unroll
        for (int e = 0; e < 2; ++e) {
            int h = e * 64 + lane;
            float q0 = b2f(r0[h]),       q1 = b2f(r1[h]);
            float k0 = b2f(r0[128 + h]), k1 = b2f(r1[128 + h]);
            float v0 = b2f(r0[256 + h]), v1 = b2f(r1[256 + h]);
            float s00 = q0 * k0, s01 = q0 * k1, s10 = q1 * k0, s11 = q1 * k1;
            for (int off = hd >> 1; off; off >>= 1) {
                s00 += __shfl_xor(s00, off);
                s01 += __shfl_xor(s01, off);
                s10 += __shfl_xor(s10, off);
                s11 += __shfl_xor(s11, off);
            }
            s00 *= scale; s01 *= scale; s10 *= scale; s11 *= scale;
            float m0 = fmaxf(s00, s01), m1 = fmaxf(s10, s11);
            float e00 = expf(s00 - m0), e01 = expf(s01 - m0);
            float e10 = expf(s10 - m1), e11 = expf(s11 - m1);
            float a00 = e00 / (e00 + e01), a01 = e01 / (e00 + e01);
            float a10 = e10 / (e10 + e11), a11 = e11 / (e10 + e11);
            ov[e] = 0.5f * ((a00 * v0 + a01 * v1) + (a10 * v0 + a11 * v1));
        }
        obar[(size_t)n * 128 + lane] = f2b(ov[0]);
        obar[(size_t)n * 128 + 64 + lane] = f2b(ov[1]);
    }
}

__device__ void edge_stage(char* smemc, int bid, int tid, int f32, const u16* h3,
                           const int* eidx, const void* Wc, const void* bc, void* out) {
    float* w0 = (float*)smemc;
    float* w1 = (float*)(smemc + 1024);
    __syncthreads();
    if (tid < 256) {
        w0[tid] = ldf(Wc, (size_t)tid * 2, f32);
        w1[tid] = ldf(Wc, (size_t)tid * 2 + 1, f32);
    }
    __syncthreads();
    int e = bid * 512 + tid;   // exactly 131072
    float a0 = ldf(bc, 0, f32), a1 = ldf(bc, 1, f32);
#pragma unroll
    for (int p = 0; p < 2; ++p) {
        int node = eidx[p * 131072 + e];
        const s8v* row = (const s8v*)(h3 + (size_t)node * 128);
#pragma unroll
        for (int cch = 0; cch < 16; ++cch) {
            s8v d = row[cch];
#pragma unroll
            for (int j = 0; j < 8; ++j) {
                float f = b2f((u16)d[j]);
                int k = p * 128 + cch * 8 + j;
                a0 += f * w0[k];
                a1 += f * w1[k];
            }
        }
    }
    if (f32) {
        ((float*)out)[(size_t)e * 2] = a0;
        ((float*)out)[(size_t)e * 2 + 1] = a1;
    } else {
        ((u16*)out)[(size_t)e * 2] = f2b(a0);
        ((u16*)out)[(size_t)e * 2 + 1] = f2b(a1);
    }
}

__global__ __launch_bounds__(512) void mega(MP P) {
    __shared__ char smem[40960];
    __shared__ int s_flag;
    cg::grid_group grid = cg::this_grid();
    const int tid = threadIdx.x, bid = blockIdx.x;
    const int gid = bid * 512 + tid;

    // dtype detect (per-block, deterministic-identical across blocks)
    if (tid == 0) s_flag = 0;
    __syncthreads();
    {
        int bad = 0;
        for (int i = tid; i < 2048; i += 512) {
            float v = b2f(((const u16*)P.G1)[i]);
            if (!(fabsf(v) <= 1e-3f)) bad = 1;
        }
        if (bad) atomicOr(&s_flag, 1);
    }
    __syncthreads();
    const int f32 = s_flag;

    // stage 0: convert G1 -> bf16 (used 6x; saves ~100 MB HBM net)
    if (f32) {
        for (size_t c = (size_t)gid; c < 2097152; c += 131072)
            *(s8v*)(P.G1b + c * 8) = load8(P.G1, c * 8, 1);
    }
    const u16* G1u = f32 ? P.G1b : (const u16*)P.G1;
    grid.sync();

    // h1 = relu(G1 @ (x W1 + b1))
    feat_stage(smem, bid, tid, f32, P.x, f32, P.W1, P.b1, 0, 4096, 128, 1, P.Zt0, 0, 0);
    grid.sync();
    big_stage(smem, tid, bid, G1u, 0, P.Zt0, P.part0);
    grid.sync();
    epi_one(gid, P.part0, 0, P.h1, 0, 1.0f);
    grid.sync();

    // batch-3 feats from h1
    feat_stage(smem, bid, tid, f32, P.h1, 0, P.W2,  P.b2,  0, 4096, 128, 1, P.Zt1, 0, 0);
    feat_stage(smem, bid, tid, f32, P.h1, 0, P.W1h, P.b1h, 0, 4096, 128, 1, P.Zt2, 0, 0);
    feat_stage(smem, bid, tid, f32, P.h1, 0, P.W3h, P.b3h, 0, 4096, 128, 1, P.Zt3, 0, 0);
    grid.sync();
    big_stage(smem, tid, bid, G1u, 0, P.Zt1, P.part0);
    big_stage(smem, tid, bid, G1u, 0, P.Zt2, P.part1);
    big_stage(smem, tid, bid, P.G3, f32, P.Zt3, P.part2);
    grid.sync();
    epi_one(gid, P.part0, P.h1, P.h2, 1, 1.0f);
    epi_one(gid, P.part1, 0, P.Ph1, 3, 1.0f);
    epi_one(gid, P.part2, 0, P.Ph3, 3, 1.0f);
    grid.sync();

    // mixup (perm identity: hg[perm][:,perm]@Z[perm] == (hg@Z)[perm]) + featC
    mix_stage(gid, P.Ph1, P.Ph3, P.perm, ldf(P.lam, 0, f32), P.xin);
    feat_stage(smem, bid, tid, f32, P.h2, 0, P.W3, P.b3, 0, 4096, 128, 1, P.Zt0, 0, 0);
    grid.sync();
    big_stage(smem, tid, bid, G1u, 0, P.Zt0, P.part0);
    feat_stage(smem, bid, tid, f32, P.xin, 0, P.Wqkv_mix, P.bqkv_mix, 1, 8192, 384, 0, P.qkv, 0, 0);
    grid.sync();
    epi_one(gid, P.part0, P.h2, P.h3c1, 1, 1.0f);
    attn_stage(bid, tid, P.qkv, P.obar, 2);
    grid.sync();
    feat_stage(smem, bid, tid, f32, P.obar, 0, P.Wo_mix, P.bo_mix, 1, 4096, 128, 0, P.h1mix, 0, 0);
    grid.sync();

    // h2_mix / h3_c2 chain
    feat_stage(smem, bid, tid, f32, P.h1mix, 0, P.W2m, P.b2m, 0, 4096, 128, 1, P.Zt0, 0, 0);
    grid.sync();
    big_stage(smem, tid, bid, G1u, 0, P.Zt0, P.part0);
    grid.sync();
    epi_one(gid, P.part0, P.h1mix, P.h2mix, 1, 1.0f);
    grid.sync();
    feat_stage(smem, bid, tid, f32, P.h2mix, 0, P.W3m, P.b3m, 0, 4096, 128, 1, P.Zt0, 0, 0);
    grid.sync();
    big_stage(smem, tid, bid, G1u, 0, P.Zt0, P.part0);
    grid.sync();
    epi_one(gid, P.part0, P.h2mix, P.h3c2, 2, ldf(P.beta, 0, f32));
    grid.sync();

    // fusion MHA (nh=4)
    feat_stage(smem, bid, tid, f32, P.h3c1, 0, P.Wqkv_fus, P.bqkv_fus, 1, 4096, 384, 0, P.qkv, 0, 0);
    feat_stage(smem, bid, tid, f32, P.h3c2, 0, P.Wqkv_fus, P.bqkv_fus, 1, 4096, 384, 0,
               P.qkv + (size_t)4096 * 384, 0, 0);
    grid.sync();
    attn_stage(bid, tid, P.qkv, P.obar, 4);
    grid.sync();
    feat_stage(smem, bid, tid, f32, P.obar, 0, P.Wo_fus, P.bo_fus, 1, 4096, 128, 2, P.out, P.mir, f32);
    grid.sync();
    edge_stage(smem, bid, tid, f32, P.mir, P.eidx, P.Wc, P.bc, P.out);
}

// ===========================================================================
// FALLBACK PATH: R3's proven multi-kernel pipeline (unchanged).
// ===========================================================================
__global__ void detect_kernel(const u16* __restrict__ hg, int* __restrict__ flag) {
    int lane = threadIdx.x;
    bool ok = true;
    for (int i = 0; i < 32; ++i) {
        float v = b2f(hg[lane * 32 + i]);
        ok = ok && (fabsf(v) <= 1e-3f);
    }
    unsigned long long m = __ballot(ok);
    if (lane == 0) *flag = (m == ~0ull) ? 0 : 1;
}

__global__ __launch_bounds__(512) void big_gemm(const void* __restrict__ G,
                                                const u16* __restrict__ Zt,
                                                float* __restrict__ part,
                                                int kChunkLen,
                                                const int* __restrict__ dflag) {
    __shared__ u16 At[128 * 72];
    __shared__ u16 Bt[128 * 72];
    const int f32 = *dflag;
    const int tid = threadIdx.x;
    const int rowBase = blockIdx.x * 128;
    const int kChunk = blockIdx.y * kChunkLen;
    const int w = tid >> 6, lane = tid & 63;
    const int wm = w & 1, wn = w >> 1;
    const int l15 = lane & 15, quad = lane >> 4;
    const int nIter = kChunkLen >> 6;
    const int r0 = tid >> 3, kb0 = tid & 7;
    const int r1 = 64 + (tid >> 3), kb1 = tid & 7;
    f4v acc[4][2] = {};
    for (int it = 0; it < nIter; ++it) {
        const int kBase = kChunk + it * 64;
        s8v ga0 = load8(G, (size_t)(rowBase + r0) * 4096 + kBase + kb0 * 8, f32);
        s8v gb0 = *(const s8v*)(Zt + (size_t)r0 * 4096 + kBase + kb0 * 8);
        s8v ga1 = load8(G, (size_t)(rowBase + r1) * 4096 + kBase + kb1 * 8, f32);
        s8v gb1 = *(const s8v*)(Zt + (size_t)r1 * 4096 + kBase + kb1 * 8);
        __syncthreads();
        *(s8v*)(At + r0 * 72 + kb0 * 8) = ga0;
        *(s8v*)(Bt + r0 * 72 + kb0 * 8) = gb0;
        *(s8v*)(At + r1 * 72 + kb1 * 8) = ga1;
        *(s8v*)(Bt + r1 * 72 + kb1 * 8) = gb1;
        __syncthreads();
#pragma unroll
        for (int ks = 0; ks < 2; ++ks) {
            s8v a[4], b[2];
            const int kq = ks * 4 + quad;
#pragma unroll
            for (int mi = 0; mi < 4; ++mi)
                a[mi] = *(const s8v*)(At + (wm * 64 + mi * 16 + l15) * 72 + kq * 8);
#pragma unroll
            for (int ni = 0; ni < 2; ++ni)
                b[ni] = *(const s8v*)(Bt + (wn * 32 + ni * 16 + l15) * 72 + kq * 8);
#pragma unroll
            for (int mi = 0; mi < 4; ++mi)
#pragma unroll
                for (int ni = 0; ni < 2; ++ni)
                    acc[mi][ni] = __builtin_amdgcn_mfma_f32_16x16x32_bf16(
                        a[mi], b[ni], acc[mi][ni], 0, 0, 0);
        }
    }
    float* pbase = part + (size_t)blockIdx.y * 4096 * 128;
#pragma unroll
    for (int mi = 0; mi < 4; ++mi)
#pragma unroll
        for (int ni = 0; ni < 2; ++ni) {
            int row = rowBase + wm * 64 + mi * 16 + quad * 4;
            int col = wn * 32 + ni * 16 + l15;
#pragma unroll
            for (int r = 0; r < 4; ++r)
                pbase[(size_t)(row + r) * 128 + col] = acc[mi][ni][r];
        }
}

__global__ __launch_bounds__(256) void reduce_epi(const float* __restrict__ part,
                                                  const u16* __restrict__ res,
                                                  const void* __restrict__ betap,
                                                  u16* __restrict__ out, int mode,
                                                  int S, const int* __restrict__ dflag) {
    int i = (blockIdx.x * 256 + threadIdx.x) * 4;
    f4v t = {};
    for (int s = 0; s < S; ++s)
        t += *(const f4v*)(part + (size_t)s * 524288 + i);
    float bscale = (mode == 2) ? ldf(betap, 0, *dflag) : 1.0f;
    u16 o[4];
#pragma unroll
    for (int j = 0; j < 4; ++j) {
        float v = t[j];
        if (mode == 1 || mode == 2) v += b2f(res[i + j]);
        if (mode <= 2) v = fmaxf(v, 0.0f);
        if (mode == 2) v *= bscale;
        o[j] = f2b(v);
    }
    *(ushort4*)(out + i) = make_ushort4(o[0], o[1], o[2], o[3]);
}

__global__ __launch_bounds__(256) void feat_gemm(const void* __restrict__ A,
                                                 const void* __restrict__ W,
                                                 const void* __restrict__ bias,
                                                 void* __restrict__ out,
                                                 u16* __restrict__ mirror,
                                                 size_t outOfs,
                                                 int M, int NcTotal, int wLayout,
                                                 int outMode, int aRaw, int outRaw,
                                                 const int* __restrict__ dflag) {
    __shared__ char smemf[52224];
    u16* Wt = (u16*)smemf;
    u16* At = (u16*)(smemf + 34816);
    u16* Tt = (u16*)smemf;
    const int f32 = *dflag;
    const int aF32 = aRaw & f32;
    const int tid = threadIdx.x;
    const int rowBase = blockIdx.x * 64;
    const int colBase = blockIdx.y * 128;
    if (wLayout == 1) {
#pragma unroll
        for (int i = 0; i < 8; ++i) {
            int c = i * 256 + tid;
            int n = c >> 4, kb = c & 15;
            *(s8v*)(Wt + n * 136 + kb * 8) = load8(W, (size_t)(colBase + n) * 128 + kb * 8, f32);
        }
    } else {
#pragma unroll
        for (int i = 0; i < 64; ++i) {
            int idx = i * 256 + tid;
            int k = idx >> 7, n = idx & 127;
            Wt[n * 136 + k] = f2b(ldf(W, (size_t)k * NcTotal + colBase + n, f32));
        }
    }
#pragma unroll
    for (int i = 0; i < 4; ++i) {
        int c = i * 256 + tid;
        int r = c >> 4, kb = c & 15;
        *(s8v*)(At + r * 136 + kb * 8) = load8(A, (size_t)(rowBase + r) * 128 + kb * 8, aF32);
    }
    __syncthreads();
    const int w = tid >> 6, lane = tid & 63, l15 = lane & 15, quad = lane >> 4;
    f4v acc[8] = {};
#pragma unroll
    for (int ks = 0; ks < 4; ++ks) {
        int k = ks * 32 + quad * 8;
        s8v a = *(const s8v*)(At + (w * 16 + l15) * 136 + k);
#pragma unroll
        for (int ni = 0; ni < 8; ++ni) {
            s8v b = *(const s8v*)(Wt + (ni * 16 + l15) * 136 + k);
            acc[ni] = __builtin_amdgcn_mfma_f32_16x16x32_bf16(a, b, acc[ni], 0, 0, 0);
        }
    }
    if (outMode == 0) {
#pragma unroll
        for (int ni = 0; ni < 8; ++ni) {
            int n = colBase + ni * 16 + l15;
            float bv = ldf(bias, n, f32);
#pragma unroll
            for (int r = 0; r < 4; ++r) {
                int row = rowBase + w * 16 + quad * 4 + r;
                size_t idx = (size_t)row * NcTotal + n;
                float v = acc[ni][r] + bv;
                u16 vb = f2b(v);
                if (outRaw && f32) ((float*)out)[outOfs + idx] = v;
                else               ((u16*)out)[outOfs + idx] = vb;
                if (mirror) mirror[idx] = vb;
            }
        }
    } else {
        __syncthreads();
#pragma unroll
        for (int ni = 0; ni < 8; ++ni) {
            int n = ni * 16 + l15;
            float bv = ldf(bias, colBase + n, f32);
#pragma unroll
            for (int r = 0; r < 4; ++r)
                Tt[n * 72 + (w * 16 + quad * 4 + r)] = f2b(acc[ni][r] + bv);
        }
        __syncthreads();
#pragma unroll
        for (int i = 0; i < 4; ++i) {
            int c = i * 256 + tid;
            int h = c >> 3, nb = c & 7;
            s8v v = *(const s8v*)(Tt + h * 72 + nb * 8);
            *(s8v*)((u16*)out + (size_t)(colBase + h) * M + rowBase + nb * 8) = v;
        }
    }
}

__global__ __launch_bounds__(256) void mix_kernel(const u16* __restrict__ Ph1,
                                                  const u16* __restrict__ Ph3,
                                                  const int* __restrict__ perm,
                                                  const void* __restrict__ lamp,
                                                  u16* __restrict__ xin,
                                                  const int* __restrict__ dflag) {
    int i = blockIdx.x * 256 + threadIdx.x;
    int n = i >> 7, h = i & 127;
    float l = ldf(lamp, 0, *dflag);
    int pn = perm[n];
    float a = l * b2f(Ph1[i]) + (1.0f - l) * b2f(Ph1[(size_t)pn * 128 + h]);
    float b = l * b2f(Ph3[i]) + (1.0f - l) * b2f(Ph3[(size_t)pn * 128 + h]);
    xin[i] = f2b(a);
    xin[524288 + i] = f2b(b);
}

__global__ __launch_bounds__(256) void attn_kernel(const u16* __restrict__ qkv,
                                                   u16* __restrict__ obar, int nh) {
    int wid = threadIdx.x >> 6, lane = threadIdx.x & 63;
    int n = blockIdx.x * 4 + wid;
    const u16* r0 = qkv + (size_t)n * 384;
    const u16* r1 = qkv + (size_t)(4096 + n) * 384;
    int hd = 128 / nh;
    float scale = 1.0f / sqrtf((float)hd);
    float ov[2];
#pragma unroll
    for (int e = 0; e < 2; ++e) {
        int h = e * 64 + lane;
        float q0 = b2f(r0[h]),       q1 = b2f(r1[h]);
        float k0 = b2f(r0[128 + h]), k1 = b2f(r1[128 + h]);
        float v0 = b2f(r0[256 + h]), v1 = b2f(r1[256 + h]);
        float s00 = q0 * k0, s01 = q0 * k1, s10 = q1 * k0, s11 = q1 * k1;
        for (int off = hd >> 1; off; off >>= 1) {
            s00 += __shfl_xor(s00, off);
            s01 += __shfl_xor(s01, off);
            s10 += __shfl_xor(s10, off);
            s11 += __shfl_xor(s11, off);
        }
        s00 *= scale; s01 *= scale; s10 *= scale; s11 *= scale;
        float m0 = fmaxf(s00, s01), m1 = fmaxf(s10, s11);
        float e00 = expf(s00 - m0), e01 = expf(s01 - m0);
        float e10 = expf(s10 - m1), e11 = expf(s11 - m1);
        float a00 = e00 / (e00 + e01), a01 = e01 / (e00 + e01);
        float a10 = e10 / (e10 + e11), a11 = e11 / (e10 + e11);
        ov[e] = 0.5f * ((a00 * v0 + a01 * v1) + (a10 * v0 + a11 * v1));
    }
    obar[(size_t)n * 128 + lane] = f2b(ov[0]);
    obar[(size_t)n * 128 + 64 + lane] = f2b(ov[1]);
}

__global__ __launch_bounds__(256) void edge_kernel(const u16* __restrict__ h3,
                                                   const int* __restrict__ eidx,
                                                   const void* __restrict__ Wc,
                                                   const void* __restrict__ bc,
                                                   void* __restrict__ out,
                                                   const int* __restrict__ dflag) {
    __shared__ float w0[256], w1[256];
    const int f32 = *dflag;
    int t = threadIdx.x;
    w0[t] = ldf(Wc, (size_t)t * 2, f32);
    w1[t] = ldf(Wc, (size_t)t * 2 + 1, f32);
    __syncthreads();
    int e = blockIdx.x * 256 + t;
    float a0 = ldf(bc, 0, f32), a1 = ldf(bc, 1, f32);
#pragma unroll
    for (int p = 0; p < 2; ++p) {
        int node = eidx[p * 131072 + e];
        const s8v* row = (const s8v*)(h3 + (size_t)node * 128);
#pragma unroll
        for (int cch = 0; cch < 16; ++cch) {
            s8v d = row[cch];
#pragma unroll
            for (int j = 0; j < 8; ++j) {
                float f = b2f((u16)d[j]);
                int k = p * 128 + cch * 8 + j;
                a0 += f * w0[k];
                a1 += f * w1[k];
            }
        }
    }
    if (f32) {
        ((float*)out)[(size_t)e * 2] = a0;
        ((float*)out)[(size_t)e * 2 + 1] = a1;
    } else {
        ((u16*)out)[(size_t)e * 2] = f2b(a0);
        ((u16*)out)[(size_t)e * 2 + 1] = f2b(a1);
    }
}

// ---------------------------------------------------------------------------
extern "C" void kernel_launch(void* const* d_in, const int* in_sizes, int n_in,
                              void* d_out, int out_size, void* d_ws, size_t ws_size,
                              hipStream_t stream) {
    const size_t MB = 1ull << 20;
    char* base = (char*)d_ws;

    MP P;
    P.x = d_in[0]; P.G1 = d_in[1]; P.G3 = d_in[2];
    P.eidx = (const int*)d_in[3]; P.perm = (const int*)d_in[4];
    P.lam = d_in[5]; P.beta = d_in[6];
    P.W1 = d_in[7];  P.b1 = d_in[8];
    P.W2 = d_in[9];  P.b2 = d_in[10];
    P.W3 = d_in[11]; P.b3 = d_in[12];
    P.W1h = d_in[13]; P.b1h = d_in[14];
    P.W3h = d_in[15]; P.b3h = d_in[16];
    P.W2m = d_in[17]; P.b2m = d_in[18];
    P.W3m = d_in[19]; P.b3m = d_in[20];
    P.Wqkv_mix = d_in[21]; P.bqkv_mix = d_in[22];
    P.Wo_mix = d_in[23];   P.bo_mix = d_in[24];
    P.Wqkv_fus = d_in[25]; P.bqkv_fus = d_in[26];
    P.Wo_fus = d_in[27];   P.bo_fus = d_in[28];
    P.Wc = d_in[29]; P.bc = d_in[30];
    P.out = d_out;
    P.G1b   = (u16*)(base);              // 32 MB
    P.part0 = (float*)(base + 32 * MB);  // 16 MB
    P.part1 = (float*)(base + 48 * MB);  // 16 MB
    P.part2 = (float*)(base + 64 * MB);  // 16 MB
    P.Zt0   = (u16*)(base + 80 * MB);
    P.Zt1   = (u16*)(base + 81 * MB);
    P.Zt2   = (u16*)(base + 82 * MB);
    P.Zt3   = (u16*)(base + 83 * MB);
    P.h1    = (u16*)(base + 84 * MB);
    P.h2    = (u16*)(base + 85 * MB);
    P.h3c1  = (u16*)(base + 86 * MB);
    P.h1mix = (u16*)(base + 87 * MB);
    P.h2mix = (u16*)(base + 88 * MB);
    P.h3c2  = (u16*)(base + 89 * MB);
    P.Ph1   = (u16*)(base + 90 * MB);
    P.Ph3   = (u16*)(base + 91 * MB);
    P.xin   = (u16*)(base + 92 * MB);    // 2 MB
    P.qkv   = (u16*)(base + 94 * MB);    // 6 MB
    P.obar  = (u16*)(base + 100 * MB);
    P.mir   = (u16*)(base + 101 * MB);   // ends at 102 MB

    hipError_t err = hipErrorUnknown;
    if (ws_size >= 102 * MB) {
        void* args[] = { &P };
        err = hipLaunchCooperativeKernel((const void*)mega, dim3(256), dim3(512),
                                         args, 0, stream);
    }
    if (err == hipSuccess) return;
    (void)hipGetLastError();  // clear error state; fall back to R3 path

    // ---------------- R3 fallback ----------------
    u16* Zt    = (u16*)(base + 0 * MB);
    u16* h1    = (u16*)(base + 1 * MB);
    u16* h2    = (u16*)(base + 2 * MB);
    u16* h3c1  = (u16*)(base + 3 * MB);
    u16* h1mix = (u16*)(base + 4 * MB);
    u16* h2mix = (u16*)(base + 5 * MB);
    u16* h3c2  = (u16*)(base + 6 * MB);
    u16* Ph1   = (u16*)(base + 7 * MB);
    u16* Ph3   = (u16*)(base + 8 * MB);
    int* dflag = (int*)(base + 9 * MB);
    char* pool = base + 9 * MB + 65536;
    size_t poolBytes = (ws_size > 9 * MB + 65536) ? ws_size - 9 * MB - 65536 : 0;
    int S = (poolBytes >= 16 * MB) ? 8 : (poolBytes >= 8 * MB) ? 4
          : (poolBytes >= 4 * MB) ? 2 : 1;
    int kLen = 4096 / S;
    float* part = (float*)pool;
    u16* xin  = (u16*)pool;
    u16* qkv  = (u16*)(pool + 2 * MB);
    u16* obar = (u16*)pool;

    auto feat = [&](const void* A, const void* W, const void* b, void* o,
                    u16* mir, size_t ofs, int M, int Nc, int wl, int om,
                    int aRaw, int oRaw) {
        feat_gemm<<<dim3(M / 64, Nc / 128), 256, 0, stream>>>(
            A, W, b, o, mir, ofs, M, Nc, wl, om, aRaw, oRaw, dflag);
    };
    auto big = [&](const void* Gm) {
        big_gemm<<<dim3(32, S), 512, 0, stream>>>(Gm, Zt, part, kLen, dflag);
    };
    auto epi = [&](const u16* res, u16* o, int mode) {
        reduce_epi<<<512, 256, 0, stream>>>(part, res, P.beta, o, mode, S, dflag);
    };

    detect_kernel<<<1, 64, 0, stream>>>((const u16*)P.G1, dflag);
    feat(P.x, P.W1, P.b1, Zt, nullptr, 0, 4096, 128, 0, 1, 1, 0);  big(P.G1);  epi(nullptr, h1, 0);
    feat(h1, P.W2, P.b2, Zt, nullptr, 0, 4096, 128, 0, 1, 0, 0); big(P.G1);  epi(h1, h2, 1);
    feat(h1, P.W1h, P.b1h, Zt, nullptr, 0, 4096, 128, 0, 1, 0, 0); big(P.G1); epi(nullptr, Ph1, 3);
    feat(h1, P.W3h, P.b3h, Zt, nullptr, 0, 4096, 128, 0, 1, 0, 0); big(P.G3); epi(nullptr, Ph3, 3);
    feat(h2, P.W3, P.b3, Zt, nullptr, 0, 4096, 128, 0, 1, 0, 0); big(P.G1);  epi(h2, h3c1, 1);
    mix_kernel<<<2048, 256, 0, stream>>>(Ph1, Ph3, P.perm, P.lam, xin, dflag);
    feat(xin, P.Wqkv_mix, P.bqkv_mix, qkv, nullptr, 0, 8192, 384, 1, 0, 0, 0);
    attn_kernel<<<1024, 256, 0, stream>>>(qkv, obar, 2);
    feat(obar, P.Wo_mix, P.bo_mix, h1mix, nullptr, 0, 4096, 128, 1, 0, 0, 0);
    feat(h1mix, P.W2m, P.b2m, Zt, nullptr, 0, 4096, 128, 0, 1, 0, 0); big(P.G1); epi(h1mix, h2mix, 1);
    feat(h2mix, P.W3m, P.b3m, Zt, nullptr, 0, 4096, 128, 0, 1, 0, 0); big(P.G1); epi(h2mix, h3c2, 2);
    feat(h3c1, P.Wqkv_fus, P.bqkv_fus, qkv, nullptr, 0, 4096, 384, 1, 0, 0, 0);
    feat(h3c2, P.Wqkv_fus, P.bqkv_fus, qkv + (size_t)4096 * 384, nullptr, 0, 4096, 384, 1, 0, 0, 0);
    attn_kernel<<<1024, 256, 0, stream>>>(qkv, obar, 4);
    feat(obar, P.Wo_fus, P.bo_fus, d_out, Zt, (size_t)131072 * 2, 4096, 128, 1, 0, 0, 1);
    edge_kernel<<<512, 256, 0, stream>>>(Zt, P.eidx, P.Wc, P.bc, d_out, dflag);
}

// Round 5
// 540.060 us; speedup vs baseline: 2.0289x; 2.0289x over previous
//
#include <hip/hip_runtime.h>
#include <math.h>

typedef unsigned short u16;
typedef short s8v __attribute__((ext_vector_type(8)));   // 8 bf16 = one MFMA A/B frag
typedef float f4v __attribute__((ext_vector_type(4)));   // MFMA C/D frag

__device__ inline float b2f(u16 u) {
    union { unsigned int i; float f; } v; v.i = ((unsigned int)u) << 16; return v.f;
}
__device__ inline u16 f2b(float f) {  // round-to-nearest-even
    unsigned int x = __float_as_uint(f);
    return (u16)((x + 0x7fffu + ((x >> 16) & 1u)) >> 16);
}
__device__ inline float ldf(const void* p, size_t i, int f32) {
    return f32 ? ((const float*)p)[i] : b2f(((const u16*)p)[i]);
}
__device__ inline s8v load8(const void* p, size_t idx, int f32) {
    if (f32) {
        const float* f = (const float*)p + idx;
        float4 a = *(const float4*)(f);
        float4 b = *(const float4*)(f + 4);
        s8v r;
        r[0] = (short)f2b(a.x); r[1] = (short)f2b(a.y);
        r[2] = (short)f2b(a.z); r[3] = (short)f2b(a.w);
        r[4] = (short)f2b(b.x); r[5] = (short)f2b(b.y);
        r[6] = (short)f2b(b.z); r[7] = (short)f2b(b.w);
        return r;
    }
    return *(const s8v*)((const u16*)p + idx);
}

// ---------------------------------------------------------------------------
// detect dtype (per-block, deterministic) + convert G1 -> bf16 (G1 used 6x).
// grid 1024 x 256. When doCopy==0 (low-ws tier) only the flag is written.
// ---------------------------------------------------------------------------
__global__ __launch_bounds__(256) void convert_g1(const void* __restrict__ G1,
                                                  u16* __restrict__ G1b,
                                                  int* __restrict__ dflag,
                                                  int doCopy) {
    __shared__ int s_flag;
    const int tid = threadIdx.x, bid = blockIdx.x;
    if (tid == 0) s_flag = 0;
    __syncthreads();
    {
        int bad = 0;
        for (int i = tid; i < 2048; i += 256) {
            float v = b2f(((const u16*)G1)[i]);
            if (!(fabsf(v) <= 1e-3f)) bad = 1;   // NaN -> bad
        }
        if (bad) atomicOr(&s_flag, 1);
    }
    __syncthreads();
    const int f32 = s_flag;
    if (bid == 0 && tid == 0) *dflag = f32;
    if (!doCopy) return;
    const int gid = bid * 256 + tid;             // 262144 threads
    for (size_t c = (size_t)gid; c < 2097152; c += 262144)
        *(s8v*)(G1b + c * 8) = load8(G1, c * 8, f32);
}

// ---------------------------------------------------------------------------
// Big propagation GEMM v2: software-pipelined, BM=64, BN=128(full), BK=64.
// grid (64, S, nz), block 256 (4 waves: 2m x 2n, each 32m x 64n).
// Prefetch next K-tile into regs before the MFMA region -> global latency
// hidden under MFMA + co-resident blocks (27 KB LDS -> 4-5 blocks/CU).
// ---------------------------------------------------------------------------
struct BigJob { const void* G; const u16* Zt; float* part; int gF32; };
struct BigP { BigJob j[3]; };

__global__ __launch_bounds__(256) void big_v2(BigP P, int kLen,
                                              const int* __restrict__ dflag) {
    __shared__ u16 At[64 * 72];
    __shared__ u16 Bt[128 * 72];
    const BigJob jb = P.j[blockIdx.z];
    const int f32 = jb.gF32 ? *dflag : 0;
    const int tid = threadIdx.x;
    const int rowBase = blockIdx.x * 64;
    const int kChunk = blockIdx.y * kLen;
    const int nIter = kLen >> 6;
    const int w = tid >> 6, lane = tid & 63;
    const int wm = w & 1, wn = w >> 1;
    const int l15 = lane & 15, quad = lane >> 4;
    const int rA0 = tid >> 3, rA1 = 32 + (tid >> 3), kb = tid & 7;
    const u16* Zt = jb.Zt;

    f4v acc[2][4] = {};
    s8v a0, a1, b0, b1, b2, b3;
    {   // prefetch it=0
        const int kBase = kChunk;
        a0 = load8(jb.G, (size_t)(rowBase + rA0) * 4096 + kBase + kb * 8, f32);
        a1 = load8(jb.G, (size_t)(rowBase + rA1) * 4096 + kBase + kb * 8, f32);
        b0 = *(const s8v*)(Zt + (size_t)(rA0) * 4096 + kBase + kb * 8);
        b1 = *(const s8v*)(Zt + (size_t)(rA0 + 32) * 4096 + kBase + kb * 8);
        b2 = *(const s8v*)(Zt + (size_t)(rA0 + 64) * 4096 + kBase + kb * 8);
        b3 = *(const s8v*)(Zt + (size_t)(rA0 + 96) * 4096 + kBase + kb * 8);
    }
    for (int it = 0; it < nIter; ++it) {
        __syncthreads();            // prior MFMA ds_reads done
        *(s8v*)(At + rA0 * 72 + kb * 8) = a0;
        *(s8v*)(At + rA1 * 72 + kb * 8) = a1;
        *(s8v*)(Bt + rA0 * 72 + kb * 8) = b0;
        *(s8v*)(Bt + (rA0 + 32) * 72 + kb * 8) = b1;
        *(s8v*)(Bt + (rA0 + 64) * 72 + kb * 8) = b2;
        *(s8v*)(Bt + (rA0 + 96) * 72 + kb * 8) = b3;
        __syncthreads();
        if (it + 1 < nIter) {       // issue next-tile loads; waited only at next ds_write
            const int kBase = kChunk + (it + 1) * 64;
            a0 = load8(jb.G, (size_t)(rowBase + rA0) * 4096 + kBase + kb * 8, f32);
            a1 = load8(jb.G, (size_t)(rowBase + rA1) * 4096 + kBase + kb * 8, f32);
            b0 = *(const s8v*)(Zt + (size_t)(rA0) * 4096 + kBase + kb * 8);
            b1 = *(const s8v*)(Zt + (size_t)(rA0 + 32) * 4096 + kBase + kb * 8);
            b2 = *(const s8v*)(Zt + (size_t)(rA0 + 64) * 4096 + kBase + kb * 8);
            b3 = *(const s8v*)(Zt + (size_t)(rA0 + 96) * 4096 + kBase + kb * 8);
        }
#pragma unroll
        for (int ks = 0; ks < 2; ++ks) {
            s8v af[2], bf[4];
            const int ko = (ks * 4 + quad) * 8;
#pragma unroll
            for (int mi = 0; mi < 2; ++mi)
                af[mi] = *(const s8v*)(At + (wm * 32 + mi * 16 + l15) * 72 + ko);
#pragma unroll
            for (int ni = 0; ni < 4; ++ni)
                bf[ni] = *(const s8v*)(Bt + (wn * 64 + ni * 16 + l15) * 72 + ko);
#pragma unroll
            for (int mi = 0; mi < 2; ++mi)
#pragma unroll
                for (int ni = 0; ni < 4; ++ni)
                    acc[mi][ni] = __builtin_amdgcn_mfma_f32_16x16x32_bf16(
                        af[mi], bf[ni], acc[mi][ni], 0, 0, 0);
        }
    }
    float* pbase = jb.part + (size_t)blockIdx.y * 524288;
#pragma unroll
    for (int mi = 0; mi < 2; ++mi)
#pragma unroll
        for (int ni = 0; ni < 4; ++ni) {
            int row = rowBase + wm * 32 + mi * 16 + quad * 4;
            int col = wn * 64 + ni * 16 + l15;
#pragma unroll
            for (int r = 0; r < 4; ++r)
                pbase[(size_t)(row + r) * 128 + col] = acc[mi][ni][r];
        }
}

// ---------------------------------------------------------------------------
// Split-K reduce + epilogue, z-batched. mode: 0=relu(t), 1=relu(t+res),
// 2=relu(t+res)*beta, 3=t.  grid (512, 1, nz) x 256.
// ---------------------------------------------------------------------------
struct EpiJob { const float* part; const u16* res; u16* out; int mode; };
struct EpiP { EpiJob j[3]; const void* betap; };

__global__ __launch_bounds__(256) void epi_v2(EpiP P, int S,
                                              const int* __restrict__ dflag) {
    const EpiJob J = P.j[blockIdx.z];
    int i = (blockIdx.x * 256 + threadIdx.x) * 4;
    f4v t = {};
    for (int s = 0; s < S; ++s)
        t += *(const f4v*)(J.part + (size_t)s * 524288 + i);
    float bscale = (J.mode == 2) ? ldf(P.betap, 0, *dflag) : 1.0f;
    u16 o[4];
#pragma unroll
    for (int k = 0; k < 4; ++k) {
        float v = t[k];
        if (J.mode == 1 || J.mode == 2) v += b2f(J.res[i + k]);
        if (J.mode <= 2) v = fmaxf(v, 0.0f);
        if (J.mode == 2) v *= bscale;
        o[k] = f2b(v);
    }
    *(ushort4*)(J.out + i) = make_ushort4(o[0], o[1], o[2], o[3]);
}

// ---------------------------------------------------------------------------
// Feature GEMM v2 (R3-validated body + z-batch + fused mixup A-mode).
// out = A[M,128] @ W + bias.  wLayout 0: W[128][Nc]; 1: W[Nc][128].
// outMode 0: bf16 [M][Nc]; 1: transposed Zt[128][M]; 2: h3 -> d_out + mirror.
// aMode 0: internal bf16; 1: raw input (dtype flag); 2: mixup of Ph1/Ph3.
// grid (M/64, Nc/128, nz), block 256.
// ---------------------------------------------------------------------------
struct FeatJob { const void* A; const void* W; const void* bias; void* out;
                 u16* mir; size_t outOfs; int wLayout; int outMode; int aMode; };
struct FeatP { FeatJob j[3]; const u16* Ph1; const u16* Ph3;
               const int* perm; const void* lam; };

__global__ __launch_bounds__(256) void feat_v2(FeatP P, int M, int NcTotal,
                                               const int* __restrict__ dflag) {
    __shared__ char smemf[52224];
    u16* Wt = (u16*)smemf;              // [128][136]
    u16* At = (u16*)(smemf + 34816);    // [64][136]
    u16* Tt = (u16*)smemf;              // [128][72], aliases Wt after MFMA+sync
    const FeatJob J = P.j[blockIdx.z];
    const int f32 = *dflag;
    const int tid = threadIdx.x;
    const int rowBase = blockIdx.x * 64;
    const int colBase = blockIdx.y * 128;

    if (J.wLayout == 1) {
#pragma unroll
        for (int i = 0; i < 8; ++i) {
            int c = i * 256 + tid;          // 2048 chunks of 8
            int n = c >> 4, kb = c & 15;
            *(s8v*)(Wt + n * 136 + kb * 8) =
                load8(J.W, (size_t)(colBase + n) * 128 + kb * 8, f32);
        }
    } else {
#pragma unroll
        for (int i = 0; i < 64; ++i) {
            int idx = i * 256 + tid;        // 16384 elems
            int k = idx >> 7, n = idx & 127;
            Wt[n * 136 + k] = f2b(ldf(J.W, (size_t)k * NcTotal + colBase + n, f32));
        }
    }
    if (J.aMode == 2) {                     // fused mixup from Ph1/Ph3
        float l = ldf(P.lam, 0, f32);
#pragma unroll
        for (int i = 0; i < 4; ++i) {
            int c = i * 256 + tid;
            int r = c >> 4, kb = c & 15;
            int grow = rowBase + r;
            const u16* src = (grow < 4096) ? P.Ph1 : P.Ph3;
            int n = grow & 4095;
            int pn = P.perm[n];
            s8v va = *(const s8v*)(src + (size_t)n * 128 + kb * 8);
            s8v vb = *(const s8v*)(src + (size_t)pn * 128 + kb * 8);
            s8v r8;
#pragma unroll
            for (int q = 0; q < 8; ++q)
                r8[q] = (short)f2b(l * b2f((u16)va[q]) + (1.0f - l) * b2f((u16)vb[q]));
            *(s8v*)(At + r * 136 + kb * 8) = r8;
        }
    } else {
        const int aF32 = (J.aMode == 1) ? f32 : 0;
#pragma unroll
        for (int i = 0; i < 4; ++i) {
            int c = i * 256 + tid;
            int r = c >> 4, kb = c & 15;
            *(s8v*)(At + r * 136 + kb * 8) =
                load8(J.A, (size_t)(rowBase + r) * 128 + kb * 8, aF32);
        }
    }
    __syncthreads();

    const int w = tid >> 6, lane = tid & 63, l15 = lane & 15, quad = lane >> 4;
    f4v acc[8] = {};
#pragma unroll
    for (int ks = 0; ks < 4; ++ks) {
        int k = ks * 32 + quad * 8;
        s8v a = *(const s8v*)(At + (w * 16 + l15) * 136 + k);
#pragma unroll
        for (int ni = 0; ni < 8; ++ni) {
            s8v b = *(const s8v*)(Wt + (ni * 16 + l15) * 136 + k);
            acc[ni] = __builtin_amdgcn_mfma_f32_16x16x32_bf16(a, b, acc[ni], 0, 0, 0);
        }
    }

    if (J.outMode == 0) {
#pragma unroll
        for (int ni = 0; ni < 8; ++ni) {
            int n = colBase + ni * 16 + l15;
            float bv = ldf(J.bias, n, f32);
#pragma unroll
            for (int r = 0; r < 4; ++r) {
                int row = rowBase + w * 16 + quad * 4 + r;
                ((u16*)J.out)[(size_t)row * NcTotal + n] = f2b(acc[ni][r] + bv);
            }
        }
    } else if (J.outMode == 2) {            // final h3 -> d_out (+ bf16 mirror)
#pragma unroll
        for (int ni = 0; ni < 8; ++ni) {
            int n = colBase + ni * 16 + l15;
            float bv = ldf(J.bias, n, f32);
#pragma unroll
            for (int r = 0; r < 4; ++r) {
                int row = rowBase + w * 16 + quad * 4 + r;
                size_t idx = (size_t)row * NcTotal + n;
                float v = acc[ni][r] + bv;
                u16 vb = f2b(v);
                J.mir[idx] = vb;
                if (f32) ((float*)J.out)[J.outOfs + idx] = v;
                else     ((u16*)J.out)[J.outOfs + idx] = vb;
            }
        }
    } else {                                // outMode 1: transposed Zt[128][M]
        __syncthreads();
#pragma unroll
        for (int ni = 0; ni < 8; ++ni) {
            int n = ni * 16 + l15;
            float bv = ldf(J.bias, colBase + n, f32);
#pragma unroll
            for (int r = 0; r < 4; ++r)
                Tt[n * 72 + (w * 16 + quad * 4 + r)] = f2b(acc[ni][r] + bv);
        }
        __syncthreads();
#pragma unroll
        for (int i = 0; i < 4; ++i) {
            int c = i * 256 + tid;
            int h = c >> 3, nb = c & 7;
            s8v v = *(const s8v*)(Tt + h * 72 + nb * 8);
            *(s8v*)((u16*)J.out + (size_t)(colBase + h) * M + rowBase + nb * 8) = v;
        }
    }
}

// ---------------------------------------------------------------------------
// L=2 self-attention + mean over L (Wo applied afterwards; mean commutes).
// ---------------------------------------------------------------------------
__global__ __launch_bounds__(256) void attn_kernel(const u16* __restrict__ qkv,
                                                   u16* __restrict__ obar, int nh) {
    int wid = threadIdx.x >> 6, lane = threadIdx.x & 63;
    int n = blockIdx.x * 4 + wid;
    const u16* r0 = qkv + (size_t)n * 384;
    const u16* r1 = qkv + (size_t)(4096 + n) * 384;
    int hd = 128 / nh;
    float scale = 1.0f / sqrtf((float)hd);
    float ov[2];
#pragma unroll
    for (int e = 0; e < 2; ++e) {
        int h = e * 64 + lane;
        float q0 = b2f(r0[h]),       q1 = b2f(r1[h]);
        float k0 = b2f(r0[128 + h]), k1 = b2f(r1[128 + h]);
        float v0 = b2f(r0[256 + h]), v1 = b2f(r1[256 + h]);
        float s00 = q0 * k0, s01 = q0 * k1, s10 = q1 * k0, s11 = q1 * k1;
        for (int off = hd >> 1; off; off >>= 1) {
            s00 += __shfl_xor(s00, off);
            s01 += __shfl_xor(s01, off);
            s10 += __shfl_xor(s10, off);
            s11 += __shfl_xor(s11, off);
        }
        s00 *= scale; s01 *= scale; s10 *= scale; s11 *= scale;
        float m0 = fmaxf(s00, s01), m1 = fmaxf(s10, s11);
        float e00 = expf(s00 - m0), e01 = expf(s01 - m0);
        float e10 = expf(s10 - m1), e11 = expf(s11 - m1);
        float a00 = e00 / (e00 + e01), a01 = e01 / (e00 + e01);
        float a10 = e10 / (e10 + e11), a11 = e11 / (e10 + e11);
        ov[e] = 0.5f * ((a00 * v0 + a01 * v1) + (a10 * v0 + a11 * v1));
    }
    obar[(size_t)n * 128 + lane] = f2b(ov[0]);
    obar[(size_t)n * 128 + 64 + lane] = f2b(ov[1]);
}

// ---------------------------------------------------------------------------
// Edge classifier: out[e] = concat(h3[i0],h3[i1]) @ Wc + bc.
// ---------------------------------------------------------------------------
__global__ __launch_bounds__(256) void edge_kernel(const u16* __restrict__ h3,
                                                   const int* __restrict__ eidx,
                                                   const void* __restrict__ Wc,
                                                   const void* __restrict__ bc,
                                                   void* __restrict__ out,
                                                   const int* __restrict__ dflag) {
    __shared__ float w0[256], w1[256];
    const int f32 = *dflag;
    int t = threadIdx.x;
    w0[t] = ldf(Wc, (size_t)t * 2, f32);
    w1[t] = ldf(Wc, (size_t)t * 2 + 1, f32);
    __syncthreads();
    int e = blockIdx.x * 256 + t;
    float a0 = ldf(bc, 0, f32), a1 = ldf(bc, 1, f32);
#pragma unroll
    for (int p = 0; p < 2; ++p) {
        int node = eidx[p * 131072 + e];
        const s8v* row = (const s8v*)(h3 + (size_t)node * 128);
#pragma unroll
        for (int cch = 0; cch < 16; ++cch) {
            s8v d = row[cch];
#pragma unroll
            for (int j = 0; j < 8; ++j) {
                float f = b2f((u16)d[j]);
                int k = p * 128 + cch * 8 + j;
                a0 += f * w0[k];
                a1 += f * w1[k];
            }
        }
    }
    if (f32) {
        ((float*)out)[(size_t)e * 2] = a0;
        ((float*)out)[(size_t)e * 2 + 1] = a1;
    } else {
        ((u16*)out)[(size_t)e * 2] = f2b(a0);
        ((u16*)out)[(size_t)e * 2 + 1] = f2b(a1);
    }
}

// ---------------------------------------------------------------------------
extern "C" void kernel_launch(void* const* d_in, const int* in_sizes, int n_in,
                              void* d_out, int out_size, void* d_ws, size_t ws_size,
                              hipStream_t stream) {
    const void* x    = d_in[0];
    const void* G1   = d_in[1];
    const void* G3   = d_in[2];
    const int* eidx = (const int*)d_in[3];
    const int* perm = (const int*)d_in[4];
    const void* lam  = d_in[5];
    const void* beta = d_in[6];
    const void* W1 = d_in[7],  *b1 = d_in[8];
    const void* W2 = d_in[9],  *b2 = d_in[10];
    const void* W3 = d_in[11], *b3 = d_in[12];
    const void* W1h = d_in[13], *b1h = d_in[14];
    const void* W3h = d_in[15], *b3h = d_in[16];
    const void* W2m = d_in[17], *b2m = d_in[18];
    const void* W3m = d_in[19], *b3m = d_in[20];
    const void* Wqkv_mix = d_in[21], *bqkv_mix = d_in[22];
    const void* Wo_mix   = d_in[23], *bo_mix   = d_in[24];
    const void* Wqkv_fus = d_in[25], *bqkv_fus = d_in[26];
    const void* Wo_fus   = d_in[27], *bo_fus   = d_in[28];
    const void* Wc = d_in[29], *bc = d_in[30];

    const size_t MB = 1ull << 20;
    char* base = (char*)d_ws;
    const bool tier1 = ws_size >= 100 * MB;   // measured ws = 256 MB
    const int Ssing = tier1 ? 16 : 4;
    const int Sbat  = tier1 ? 8 : 2;
    u16* G1b = (u16*)base;                               // 32 MB (tier1 only)
    char* pool = base + (tier1 ? 32 : 0) * MB;
    const size_t poolSz = (size_t)(tier1 ? 48 : 12) * MB;
    char* persist = pool + poolSz;
    u16* Zt0   = (u16*)(persist + 0 * MB);
    u16* Zt1   = (u16*)(persist + 1 * MB);
    u16* Zt2   = (u16*)(persist + 2 * MB);
    u16* Zt3   = (u16*)(persist + 3 * MB);
    u16* h1    = (u16*)(persist + 4 * MB);
    u16* h2    = (u16*)(persist + 5 * MB);
    u16* h3c1  = (u16*)(persist + 6 * MB);
    u16* h1mix = (u16*)(persist + 7 * MB);
    u16* h2mix = (u16*)(persist + 8 * MB);
    u16* h3c2  = (u16*)(persist + 9 * MB);
    u16* Ph1   = (u16*)(persist + 10 * MB);
    u16* Ph3   = (u16*)(persist + 11 * MB);
    u16* mir   = (u16*)(persist + 12 * MB);
    u16* qkv   = (u16*)(persist + 13 * MB);              // 6 MB
    int* dflag = (int*)(persist + 19 * MB);
    float* part0 = (float*)pool;
    float* part1 = (float*)(pool + (size_t)Sbat * 2 * MB);
    float* part2 = (float*)(pool + (size_t)2 * Sbat * 2 * MB);

    const void* G1use = tier1 ? (const void*)G1b : G1;
    const int g1F32 = tier1 ? 0 : 1;

    auto featN = [&](FeatP& FP, int nz, int M, int Nc) {
        feat_v2<<<dim3(M / 64, Nc / 128, nz), 256, 0, stream>>>(FP, M, Nc, dflag);
    };
    auto feat1 = [&](const void* A, const void* W, const void* b, void* o,
                     int M, int Nc, int wl, int om, int am,
                     u16* mr = nullptr, size_t ofs = 0) {
        FeatP FP = {};
        FP.j[0] = { A, W, b, o, mr, ofs, wl, om, am };
        FP.Ph1 = Ph1; FP.Ph3 = Ph3; FP.perm = perm; FP.lam = lam;
        featN(FP, 1, M, Nc);
    };
    auto big1 = [&](const void* Gm, int gF32, const u16* Zt, float* part) {
        BigP BP = {};
        BP.j[0] = { Gm, Zt, part, gF32 };
        big_v2<<<dim3(64, Ssing, 1), 256, 0, stream>>>(BP, 4096 / Ssing, dflag);
    };
    auto epi1 = [&](const float* part, const u16* res, u16* o, int mode) {
        EpiP EP = {};
        EP.j[0] = { part, res, o, mode };
        EP.betap = beta;
        epi_v2<<<dim3(512, 1, 1), 256, 0, stream>>>(EP, Ssing, dflag);
    };

    // 1. detect dtype + G1 -> bf16
    convert_g1<<<1024, 256, 0, stream>>>(G1, G1b, dflag, tier1 ? 1 : 0);
    // 2-4. h1 = relu(G1 @ (x W1 + b1))
    feat1(x, W1, b1, Zt0, 4096, 128, 0, 1, 1);
    big1(G1use, g1F32, Zt0, part0);
    epi1(part0, nullptr, h1, 0);
    // 5. batch-3 feats from h1 (independent)
    {
        FeatP FP = {};
        FP.j[0] = { h1, W2,  b2,  Zt1, nullptr, 0, 0, 1, 0 };
        FP.j[1] = { h1, W1h, b1h, Zt2, nullptr, 0, 0, 1, 0 };
        FP.j[2] = { h1, W3h, b3h, Zt3, nullptr, 0, 0, 1, 0 };
        FP.Ph1 = Ph1; FP.Ph3 = Ph3; FP.perm = perm; FP.lam = lam;
        featN(FP, 3, 4096, 128);
    }
    // 6. batch-3 big: G1@Zt1, G1@Zt2, G3@Zt3   (1536 blocks)
    {
        BigP BP = {};
        BP.j[0] = { G1use, Zt1, part0, g1F32 };
        BP.j[1] = { G1use, Zt2, part1, g1F32 };
        BP.j[2] = { G3,    Zt3, part2, 1 };
        big_v2<<<dim3(64, Sbat, 3), 256, 0, stream>>>(BP, 4096 / Sbat, dflag);
    }
    // 7. batch-3 epi: h2 = relu(t+h1); Ph1 = t; Ph3 = t
    {
        EpiP EP = {};
        EP.j[0] = { part0, h1, h2, 1 };
        EP.j[1] = { part1, nullptr, Ph1, 3 };
        EP.j[2] = { part2, nullptr, Ph3, 3 };
        EP.betap = beta;
        epi_v2<<<dim3(512, 1, 3), 256, 0, stream>>>(EP, Sbat, dflag);
    }
    // 8-11. h3_c1 = relu(G1 @ (h2 W3 + b3) + h2);  qkv_mix (mix fused in A-load)
    feat1(h2, W3, b3, Zt0, 4096, 128, 0, 1, 0);
    big1(G1use, g1F32, Zt0, part0);
    feat1(nullptr, Wqkv_mix, bqkv_mix, qkv, 8192, 384, 1, 0, 2);  // aMode=2: mixup
    epi1(part0, h2, h3c1, 1);
    // 12-13. MHA(nh=2) + proj
    attn_kernel<<<1024, 256, 0, stream>>>(qkv, (u16*)Zt0, 2);  // obar in Zt0
    feat1(Zt0, Wo_mix, bo_mix, h1mix, 4096, 128, 1, 0, 0);
    // 14-19. h2_mix, h3_c2
    feat1(h1mix, W2m, b2m, Zt1, 4096, 128, 0, 1, 0);
    big1(G1use, g1F32, Zt1, part0);
    epi1(part0, h1mix, h2mix, 1);
    feat1(h2mix, W3m, b3m, Zt1, 4096, 128, 0, 1, 0);
    big1(G1use, g1F32, Zt1, part0);
    epi1(part0, h2mix, h3c2, 2);
    // 20. fusion qkv (z=2: h3c1, h3c2)
    {
        FeatP FP = {};
        FP.j[0] = { h3c1, Wqkv_fus, bqkv_fus, qkv, nullptr, 0, 1, 0, 0 };
        FP.j[1] = { h3c2, Wqkv_fus, bqkv_fus, qkv + (size_t)4096 * 384, nullptr, 0, 1, 0, 0 };
        FP.Ph1 = Ph1; FP.Ph3 = Ph3; FP.perm = perm; FP.lam = lam;
        featN(FP, 2, 4096, 384);
    }
    // 21-22. MHA(nh=4) + final proj -> d_out h3 (+ bf16 mirror)
    attn_kernel<<<1024, 256, 0, stream>>>(qkv, (u16*)Zt0, 4);
    feat1(Zt0, Wo_fus, bo_fus, d_out, 4096, 128, 1, 2, 0, mir, (size_t)131072 * 2);
    // 23. edge classifier -> d_out[0..2E)
    edge_kernel<<<512, 256, 0, stream>>>(mir, eidx, Wc, bc, d_out, dflag);
}